// Round 2
// baseline (7369.769 us; speedup 1.0000x reference)
//
#include <hip/hip_runtime.h>
#include <hip/hip_bf16.h>

typedef __hip_bfloat16 bf16;
typedef unsigned int u32;
typedef unsigned short u16;
typedef __attribute__((ext_vector_type(4))) float f32x4;
typedef __attribute__((ext_vector_type(8))) short bf16x8;   // 8 bf16 = 4 VGPRs

#define MFMA_16x16x32(a, b, c) __builtin_amdgcn_mfma_f32_16x16x32_bf16((a), (b), (c), 0, 0, 0)

static constexpr int S   = 128;
static constexpr int Bsz = 16;
static constexpr int V   = 32000;
static constexpr int H   = 1024;
static constexpr int G4  = 4096;
static constexpr int NSB = S * Bsz;   // 2048

__device__ __forceinline__ void async_ld16(const void* g, void* l) {
  __builtin_amdgcn_global_load_lds((const __attribute__((address_space(1))) u32*)g,
                                   (__attribute__((address_space(3))) u32*)l, 16, 0, 0);
}

__device__ __forceinline__ float sigf(float x) { return 1.f / (1.f + __expf(-x)); }
__device__ __forceinline__ float tanhf_fast(float x) {
  float e = __expf(2.f * x);
  return 1.f - 2.f / (e + 1.f);   // no-NaN tanh
}
__device__ __forceinline__ u16 f2bf_bits(float x) {
  bf16 b = __float2bfloat16(x);
  return *(u16*)&b;
}

// ---------------------------------------------------------------------------
// fp32 -> bf16 bulk convert (n4 = count/4)
// ---------------------------------------------------------------------------
__global__ void cvt_f32_bf16_k(const float* __restrict__ in, bf16* __restrict__ out, int n4) {
  int i = blockIdx.x * 256 + threadIdx.x;
  if (i >= n4) return;
  float4 v = ((const float4*)in)[i];
  ushort4 o;
  o.x = f2bf_bits(v.x); o.y = f2bf_bits(v.y); o.z = f2bf_bits(v.z); o.w = f2bf_bits(v.w);
  ((ushort4*)out)[i] = o;
}

// ---------------------------------------------------------------------------
// Embedding gather from bf16 emb: x[n,:] = embB[tokens[n],:]
// ---------------------------------------------------------------------------
__global__ void embed_k(const int* __restrict__ tokens, const bf16* __restrict__ embB,
                        bf16* __restrict__ x) {
  const int n = blockIdx.x;
  const int tok = tokens[n];
  const uint4* src = (const uint4*)(embB + (size_t)tok * H);
  uint4* dst = (uint4*)(x + (size_t)n * H);
  dst[threadIdx.x] = src[threadIdx.x];   // 128 threads * 16B = 2 KB row
}

// ---------------------------------------------------------------------------
// C[M,N] = A[M,K] @ B[N,K]^T + bias0 + bias1   (m97-style 128x128 tile)
// A,B bf16. biases fp32. C fp32 (c_is_bf16=0) or bf16 (c_is_bf16=1).
// grid = (M/128, N/128), block = 256 (4 waves, 2x2 of 64x64)
// ---------------------------------------------------------------------------
__global__ __launch_bounds__(256, 2) void gemm_bt_k(
    const bf16* __restrict__ A, const bf16* __restrict__ Bm,
    const float* __restrict__ bias0, const float* __restrict__ bias1,
    void* __restrict__ C, int M, int N, int K, int c_is_bf16) {
  __shared__ bf16 As[128 * 32];
  __shared__ bf16 Bs[128 * 32];

  const int tid = threadIdx.x;
  const int wave = tid >> 6, lane = tid & 63;
  const int l15 = lane & 15, lq = lane >> 4;
  const int mBase = blockIdx.x * 128, nBase = blockIdx.y * 128;
  const int wm = (wave >> 1) * 64, wn = (wave & 1) * 64;

  // staging: wave w stages rows [w*16, w*16+16) and [64+w*16, ...) of the tile
  const int srow = lane >> 2;            // 0..15
  const int scol = (lane & 3) * 8;       // 16B granules across K-tile of 32
  const bf16* gA0 = A + (size_t)(mBase + wave * 16 + srow) * K + scol;
  const bf16* gA1 = A + (size_t)(mBase + 64 + wave * 16 + srow) * K + scol;
  const bf16* gB0 = Bm + (size_t)(nBase + wave * 16 + srow) * K + scol;
  const bf16* gB1 = Bm + (size_t)(nBase + 64 + wave * 16 + srow) * K + scol;
  bf16* lA0 = As + wave * 512 + lane * 8;
  bf16* lA1 = As + 2048 + wave * 512 + lane * 8;
  bf16* lB0 = Bs + wave * 512 + lane * 8;
  bf16* lB1 = Bs + 2048 + wave * 512 + lane * 8;

  const f32x4 zero4 = {0.f, 0.f, 0.f, 0.f};
  f32x4 acc[4][4];
#pragma unroll
  for (int mi = 0; mi < 4; ++mi)
#pragma unroll
    for (int ni = 0; ni < 4; ++ni) acc[mi][ni] = zero4;

  for (int kt = 0; kt < K; kt += 32) {
    async_ld16(gA0 + kt, lA0);
    async_ld16(gA1 + kt, lA1);
    async_ld16(gB0 + kt, lB0);
    async_ld16(gB1 + kt, lB1);
    __syncthreads();   // compiler emits s_waitcnt vmcnt(0) before s_barrier

    bf16x8 a[4], b[4];
#pragma unroll
    for (int mi = 0; mi < 4; ++mi)
      a[mi] = *(const bf16x8*)(As + (wm + mi * 16 + l15) * 32 + lq * 8);
#pragma unroll
    for (int ni = 0; ni < 4; ++ni)
      b[ni] = *(const bf16x8*)(Bs + (wn + ni * 16 + l15) * 32 + lq * 8);
#pragma unroll
    for (int mi = 0; mi < 4; ++mi)
#pragma unroll
      for (int ni = 0; ni < 4; ++ni)
        acc[mi][ni] = MFMA_16x16x32(a[mi], b[ni], acc[mi][ni]);
    __syncthreads();
  }

  // epilogue: D row=(lane>>4)*4+r (M), col=lane&15 (N)  [m89-verified mapping]
#pragma unroll
  for (int ni = 0; ni < 4; ++ni) {
    const int col = nBase + wn + ni * 16 + l15;
    float bv = 0.f;
    if (bias0) bv += bias0[col];
    if (bias1) bv += bias1[col];
#pragma unroll
    for (int mi = 0; mi < 4; ++mi) {
      const int row0 = mBase + wm + mi * 16 + lq * 4;
      f32x4 v = acc[mi][ni];
#pragma unroll
      for (int r = 0; r < 4; ++r) {
        const float out = v[r] + bv;
        if (c_is_bf16)
          ((bf16*)C)[(size_t)(row0 + r) * N + col] = __float2bfloat16(out);
        else
          ((float*)C)[(size_t)(row0 + r) * N + col] = out;
      }
    }
  }
}

// ---------------------------------------------------------------------------
// Persistent cooperative LSTM scan. 64 blocks x 256 threads.
// Block j owns h/c slice [j*16, j*16+16); wave g computes gate g's 16x16 tile.
// Whh (bf16) fragments held in registers (128 VGPR/lane) across all 128 steps.
// Gin = x@Wih^T + bih + bhh, bf16 [2048][4096]. hbuf = bf16 [2][16][1024].
// ---------------------------------------------------------------------------
__global__ __launch_bounds__(256, 1) void lstm_scan_k(
    const bf16* __restrict__ Gin, const bf16* __restrict__ Whh,
    const float* __restrict__ c0, bf16* __restrict__ hbuf,
    bf16* __restrict__ yout, bf16* __restrict__ hfin, float* __restrict__ cfin,
    unsigned* __restrict__ ctr) {
  const int j = blockIdx.x;
  const int tid = threadIdx.x;
  const int wave = tid >> 6, lane = tid & 63;
  const int l15 = lane & 15, lq = lane >> 4;

  __shared__ float gx[4][16][16];   // gate exchange (i,f,g,o)

  // preload this wave's Whh tile into registers, MFMA B-fragment order
  bf16x8 wreg[32];
  {
    const bf16* wrow = Whh + (size_t)(wave * 1024 + j * 16 + l15) * H + lq * 8;
#pragma unroll
    for (int ki = 0; ki < 32; ++ki) wreg[ki] = *(const bf16x8*)(wrow + ki * 32);
  }

  const int eb = tid >> 4, ek = tid & 15;   // elementwise: (batch, unit)
  const int hoff = eb * H + j * 16 + ek;
  float c_reg = c0 ? c0[hoff] : 0.f;

  for (int t = 0; t < S; ++t) {
    if (t > 0) {
      if (tid == 0) {
        const unsigned tgt = 64u * (unsigned)t;
        while (__hip_atomic_load(ctr, __ATOMIC_ACQUIRE, __HIP_MEMORY_SCOPE_AGENT) < tgt)
          __builtin_amdgcn_s_sleep(2);
        __threadfence();   // belt-and-braces L1/L2 invalidate before h reads
      }
      __syncthreads();
    }

    // gates = h @ Whh^T for this wave's 16 gate-rows; 4 independent MFMA chains
    const bf16* hsrc = hbuf + (size_t)(t & 1) * (Bsz * H) + (size_t)l15 * H + lq * 8;
    f32x4 ac0 = {0.f, 0.f, 0.f, 0.f}, ac1 = ac0, ac2 = ac0, ac3 = ac0;
#pragma unroll
    for (int ki = 0; ki < 32; ki += 4) {
      bf16x8 a0 = *(const bf16x8*)(hsrc + (ki + 0) * 32);
      bf16x8 a1 = *(const bf16x8*)(hsrc + (ki + 1) * 32);
      bf16x8 a2 = *(const bf16x8*)(hsrc + (ki + 2) * 32);
      bf16x8 a3 = *(const bf16x8*)(hsrc + (ki + 3) * 32);
      ac0 = MFMA_16x16x32(a0, wreg[ki + 0], ac0);
      ac1 = MFMA_16x16x32(a1, wreg[ki + 1], ac1);
      ac2 = MFMA_16x16x32(a2, wreg[ki + 2], ac2);
      ac3 = MFMA_16x16x32(a3, wreg[ki + 3], ac3);
    }
    f32x4 gacc = (ac0 + ac1) + (ac2 + ac3);
#pragma unroll
    for (int r = 0; r < 4; ++r) gx[wave][lq * 4 + r][l15] = gacc[r];
    __syncthreads();

    // elementwise LSTM cell update for (eb, ek)
    const size_t gbase = (size_t)(t * Bsz + eb) * G4 + j * 16 + ek;
    const float gi = gx[0][eb][ek] + __bfloat162float(Gin[gbase]);
    const float gf = gx[1][eb][ek] + __bfloat162float(Gin[gbase + 1024]);
    const float gg = gx[2][eb][ek] + __bfloat162float(Gin[gbase + 2048]);
    const float go = gx[3][eb][ek] + __bfloat162float(Gin[gbase + 3072]);
    const float iv = sigf(gi), fv = sigf(gf), gv = tanhf_fast(gg), ov = sigf(go);
    c_reg = fv * c_reg + iv * gv;
    const float hv = ov * tanhf_fast(c_reg);
    const bf16 hb = __float2bfloat16(hv);
    hbuf[(size_t)((t + 1) & 1) * (Bsz * H) + hoff] = hb;
    if (yout) yout[(size_t)(t * Bsz + eb) * H + j * 16 + ek] = hb;
    if (t == S - 1) {
      if (hfin) hfin[hoff] = hb;
      if (cfin) cfin[hoff] = c_reg;
    }

    // arrive: release h slice to all blocks
    __threadfence();
    __syncthreads();
    if (tid == 0)
      __hip_atomic_fetch_add(ctr, 1u, __ATOMIC_RELEASE, __HIP_MEMORY_SCOPE_AGENT);
  }
}

// ---------------------------------------------------------------------------
// dh_l = he_l @ latW^T + latb  (l = blockIdx.y), bf16 out [16,1024]
// he bf16, latW/latb fp32. grid (4, 2), block 256
// ---------------------------------------------------------------------------
__global__ void latent_k(const bf16* __restrict__ he0, const bf16* __restrict__ he1,
                         const float* __restrict__ latW, const float* __restrict__ latb,
                         bf16* __restrict__ dh0_out, bf16* __restrict__ dh1_out) {
  const bf16* he = blockIdx.y ? he1 : he0;
  bf16* out = blockIdx.y ? dh1_out : dh0_out;
  __shared__ bf16 hs[Bsz * H];   // 32 KB
  for (int i = threadIdx.x; i < (Bsz * H) / 8; i += 256)
    ((uint4*)hs)[i] = ((const uint4*)he)[i];
  __syncthreads();

  const int n = blockIdx.x * 256 + threadIdx.x;
  const float bv = latb[n];
  float acc[Bsz];
#pragma unroll
  for (int b = 0; b < Bsz; ++b) acc[b] = bv;
  const float* wrow = latW + (size_t)n * H;
  for (int k = 0; k < H; ++k) {
    const float w = wrow[k];
#pragma unroll
    for (int b = 0; b < Bsz; ++b) acc[b] += w * __bfloat162float(hs[b * H + k]);
  }
#pragma unroll
  for (int b = 0; b < Bsz; ++b) out[b * H + n] = __float2bfloat16(acc[b]);
}

// ---------------------------------------------------------------------------
extern "C" void kernel_launch(void* const* d_in, const int* in_sizes, int n_in,
                              void* d_out, int out_size, void* d_ws, size_t ws_size,
                              hipStream_t stream) {
  (void)in_sizes; (void)n_in; (void)out_size;

  const int*   tokens   = (const int*)d_in[0];
  const float* emb      = (const float*)d_in[1];
  const float* dec_bias = (const float*)d_in[2];
  const float* Wih0 = (const float*)d_in[3];
  const float* Whh0 = (const float*)d_in[4];
  const float* bih0 = (const float*)d_in[5];
  const float* bhh0 = (const float*)d_in[6];
  const float* Wih1 = (const float*)d_in[7];
  const float* Whh1 = (const float*)d_in[8];
  const float* bih1 = (const float*)d_in[9];
  const float* bhh1 = (const float*)d_in[10];
  const float* latW = (const float*)d_in[11];
  const float* latb = (const float*)d_in[12];

  char* ws = (char*)d_ws;
  size_t off = 0;
  auto alloc = [&](size_t bytes) -> char* {
    char* p = ws + off;
    off += (bytes + 255) & ~(size_t)255;
    return p;
  };
  bf16* embB  = (bf16*)alloc((size_t)V * H * 2);     // 65.5 MB
  bf16* Wih0b = (bf16*)alloc((size_t)G4 * H * 2);    // 8.4 MB
  bf16* Whh0b = (bf16*)alloc((size_t)G4 * H * 2);
  bf16* Wih1b = (bf16*)alloc((size_t)G4 * H * 2);
  bf16* Whh1b = (bf16*)alloc((size_t)G4 * H * 2);
  bf16* x     = (bf16*)alloc((size_t)NSB * H * 2);   // 4.2 MB
  bf16* G0    = (bf16*)alloc((size_t)NSB * G4 * 2);  // 16.8 MB
  bf16* G1    = (bf16*)alloc((size_t)NSB * G4 * 2);  // reused as G2
  bf16* y0    = (bf16*)alloc((size_t)NSB * H * 2);
  bf16* d0b   = (bf16*)alloc((size_t)NSB * H * 2);
  bf16* d1b   = (bf16*)alloc((size_t)NSB * H * 2);
  bf16* hbuf  = (bf16*)alloc((size_t)2 * Bsz * H * 2);
  bf16* he0   = (bf16*)alloc((size_t)Bsz * H * 2);
  bf16* he1   = (bf16*)alloc((size_t)Bsz * H * 2);
  float* ce0  = (float*)alloc((size_t)Bsz * H * 4);
  float* ce1  = (float*)alloc((size_t)Bsz * H * 4);
  bf16* dh1   = (bf16*)alloc((size_t)Bsz * H * 2);
  unsigned* ctrs = (unsigned*)alloc(1024);
  if (off > ws_size) return;   // ws too small: leaves out zeroed (diagnosable)

  unsigned* ctr0 = ctrs;
  unsigned* ctr1 = ctrs + 32;
  unsigned* ctr2 = ctrs + 64;
  unsigned* ctr3 = ctrs + 96;
  hipMemsetAsync(ctrs, 0, 1024, stream);

  auto cvt = [&](const float* src, bf16* dst, int n) {
    cvt_f32_bf16_k<<<(n / 4 + 255) / 256, 256, 0, stream>>>(src, dst, n / 4);
  };
  cvt(emb, embB, V * H);
  cvt(Wih0, Wih0b, G4 * H);
  cvt(Whh0, Whh0b, G4 * H);
  cvt(Wih1, Wih1b, G4 * H);
  cvt(Whh1, Whh1b, G4 * H);

  // x = embB[tokens]
  embed_k<<<NSB, 128, 0, stream>>>(tokens, embB, x);

  // G0 = x @ Wih0^T + (bih0 + bhh0)   -- shared by enc0 and dec0
  gemm_bt_k<<<dim3(NSB / 128, G4 / 128), 256, 0, stream>>>(
      x, Wih0b, bih0, bhh0, (void*)G0, NSB, G4, H, 1);

  // enc0
  hipMemsetAsync(hbuf, 0, (size_t)Bsz * H * 2, stream);
  {
    const float* c0p = nullptr; bf16* yo = y0; bf16* hf = he0; float* cf = ce0;
    const bf16* gp = G0; const bf16* wp = Whh0b; unsigned* cp = ctr0; bf16* hb = hbuf;
    void* args[] = {&gp, &wp, &c0p, &hb, &yo, &hf, &cf, &cp};
    hipLaunchCooperativeKernel((void*)lstm_scan_k, dim3(64), dim3(256), args, 0, stream);
  }

  // G1 = y0 @ Wih1^T + (bih1 + bhh1)
  gemm_bt_k<<<dim3(NSB / 128, G4 / 128), 256, 0, stream>>>(
      y0, Wih1b, bih1, bhh1, (void*)G1, NSB, G4, H, 1);

  // enc1 (only finals needed)
  hipMemsetAsync(hbuf, 0, (size_t)Bsz * H * 2, stream);
  {
    const float* c0p = nullptr; bf16* yo = nullptr; bf16* hf = he1; float* cf = ce1;
    const bf16* gp = G1; const bf16* wp = Whh1b; unsigned* cp = ctr1; bf16* hb = hbuf;
    void* args[] = {&gp, &wp, &c0p, &hb, &yo, &hf, &cf, &cp};
    hipLaunchCooperativeKernel((void*)lstm_scan_k, dim3(64), dim3(256), args, 0, stream);
  }

  // latent: dh0 -> hbuf slot 0 (dec0 initial h), dh1 -> side buffer
  latent_k<<<dim3(4, 2), 256, 0, stream>>>(he0, he1, latW, latb, hbuf, dh1);

  // dec0: Gin = G0 (teacher-forced same x), init (dh0, ce0)
  {
    const float* c0p = ce0; bf16* yo = d0b; bf16* hf = nullptr; float* cf = nullptr;
    const bf16* gp = G0; const bf16* wp = Whh0b; unsigned* cp = ctr2; bf16* hb = hbuf;
    void* args[] = {&gp, &wp, &c0p, &hb, &yo, &hf, &cf, &cp};
    hipLaunchCooperativeKernel((void*)lstm_scan_k, dim3(64), dim3(256), args, 0, stream);
  }

  // G2 = d0 @ Wih1^T + (bih1 + bhh1)  (reuse G1 buffer)
  gemm_bt_k<<<dim3(NSB / 128, G4 / 128), 256, 0, stream>>>(
      d0b, Wih1b, bih1, bhh1, (void*)G1, NSB, G4, H, 1);

  // dec1: init (dh1, ce1)
  hipMemcpyAsync(hbuf, dh1, (size_t)Bsz * H * 2, hipMemcpyDeviceToDevice, stream);
  {
    const float* c0p = ce1; bf16* yo = d1b; bf16* hf = nullptr; float* cf = nullptr;
    const bf16* gp = G1; const bf16* wp = Whh1b; unsigned* cp = ctr3; bf16* hb = hbuf;
    void* args[] = {&gp, &wp, &c0p, &hb, &yo, &hf, &cf, &cp};
    hipLaunchCooperativeKernel((void*)lstm_scan_k, dim3(64), dim3(256), args, 0, stream);
  }

  // logits = d1 @ embB^T + dec_bias  -> fp32 d_out [2048][32000]
  gemm_bt_k<<<dim3(NSB / 128, V / 128), 256, 0, stream>>>(
      d1b, embB, dec_bias, nullptr, d_out, NSB, V, H, 0);
}

// Round 3
// 3794.952 us; speedup vs baseline: 1.9420x; 1.9420x over previous
//
#include <hip/hip_runtime.h>
#include <hip/hip_bf16.h>

typedef __hip_bfloat16 bf16;
typedef unsigned int u32;
typedef unsigned short u16;
typedef __attribute__((ext_vector_type(4))) float f32x4;
typedef __attribute__((ext_vector_type(8))) short bf16x8;   // 8 bf16 = 4 VGPRs

#define MFMA_16x16x32(a, b, c) __builtin_amdgcn_mfma_f32_16x16x32_bf16((a), (b), (c), 0, 0, 0)

static constexpr int S   = 128;
static constexpr int Bsz = 16;
static constexpr int V   = 32000;
static constexpr int H   = 1024;
static constexpr int G4  = 4096;
static constexpr int NSB = S * Bsz;       // 2048
static constexpr int FSTRIDE = 32;        // flag stride in u32 (128 B apart)

__device__ __forceinline__ void async_ld16(const void* g, void* l) {
  __builtin_amdgcn_global_load_lds((const __attribute__((address_space(1))) u32*)g,
                                   (__attribute__((address_space(3))) u32*)l, 16, 0, 0);
}

__device__ __forceinline__ float sigf(float x) { return 1.f / (1.f + __expf(-x)); }
__device__ __forceinline__ float tanhf_fast(float x) {
  float e = __expf(2.f * x);
  return 1.f - 2.f / (e + 1.f);   // no-NaN tanh
}
__device__ __forceinline__ u32 f2bf_bits(float x) {
  bf16 b = __float2bfloat16(x);
  return (u32)*(u16*)&b;
}

// ---------------------------------------------------------------------------
// fp32 -> bf16 bulk convert (n4 = count/4)
// ---------------------------------------------------------------------------
__global__ void cvt_f32_bf16_k(const float* __restrict__ in, bf16* __restrict__ out, int n4) {
  int i = blockIdx.x * 256 + threadIdx.x;
  if (i >= n4) return;
  float4 v = ((const float4*)in)[i];
  ushort4 o;
  o.x = (u16)f2bf_bits(v.x); o.y = (u16)f2bf_bits(v.y);
  o.z = (u16)f2bf_bits(v.z); o.w = (u16)f2bf_bits(v.w);
  ((ushort4*)out)[i] = o;
}

// ---------------------------------------------------------------------------
// Embedding gather from bf16 emb: x[n,:] = embB[tokens[n],:]
// ---------------------------------------------------------------------------
__global__ void embed_k(const int* __restrict__ tokens, const bf16* __restrict__ embB,
                        bf16* __restrict__ x) {
  const int n = blockIdx.x;
  const int tok = tokens[n];
  const uint4* src = (const uint4*)(embB + (size_t)tok * H);
  uint4* dst = (uint4*)(x + (size_t)n * H);
  dst[threadIdx.x] = src[threadIdx.x];   // 128 threads * 16B = 2 KB row
}

// ---------------------------------------------------------------------------
// C[M,N] = A[M,K] @ B[N,K]^T + bias0 + bias1   (m97-style 128x128 tile)
// A,B bf16. biases fp32. C fp32 (c_is_bf16=0) or bf16 (c_is_bf16=1).
// ---------------------------------------------------------------------------
__global__ __launch_bounds__(256, 2) void gemm_bt_k(
    const bf16* __restrict__ A, const bf16* __restrict__ Bm,
    const float* __restrict__ bias0, const float* __restrict__ bias1,
    void* __restrict__ C, int M, int N, int K, int c_is_bf16) {
  __shared__ bf16 As[128 * 32];
  __shared__ bf16 Bs[128 * 32];

  const int tid = threadIdx.x;
  const int wave = tid >> 6, lane = tid & 63;
  const int l15 = lane & 15, lq = lane >> 4;
  const int mBase = blockIdx.x * 128, nBase = blockIdx.y * 128;
  const int wm = (wave >> 1) * 64, wn = (wave & 1) * 64;

  const int srow = lane >> 2;            // 0..15
  const int scol = (lane & 3) * 8;       // 16B granules across K-tile of 32
  const bf16* gA0 = A + (size_t)(mBase + wave * 16 + srow) * K + scol;
  const bf16* gA1 = A + (size_t)(mBase + 64 + wave * 16 + srow) * K + scol;
  const bf16* gB0 = Bm + (size_t)(nBase + wave * 16 + srow) * K + scol;
  const bf16* gB1 = Bm + (size_t)(nBase + 64 + wave * 16 + srow) * K + scol;
  bf16* lA0 = As + wave * 512 + lane * 8;
  bf16* lA1 = As + 2048 + wave * 512 + lane * 8;
  bf16* lB0 = Bs + wave * 512 + lane * 8;
  bf16* lB1 = Bs + 2048 + wave * 512 + lane * 8;

  const f32x4 zero4 = {0.f, 0.f, 0.f, 0.f};
  f32x4 acc[4][4];
#pragma unroll
  for (int mi = 0; mi < 4; ++mi)
#pragma unroll
    for (int ni = 0; ni < 4; ++ni) acc[mi][ni] = zero4;

  for (int kt = 0; kt < K; kt += 32) {
    async_ld16(gA0 + kt, lA0);
    async_ld16(gA1 + kt, lA1);
    async_ld16(gB0 + kt, lB0);
    async_ld16(gB1 + kt, lB1);
    __syncthreads();

    bf16x8 a[4], b[4];
#pragma unroll
    for (int mi = 0; mi < 4; ++mi)
      a[mi] = *(const bf16x8*)(As + (wm + mi * 16 + l15) * 32 + lq * 8);
#pragma unroll
    for (int ni = 0; ni < 4; ++ni)
      b[ni] = *(const bf16x8*)(Bs + (wn + ni * 16 + l15) * 32 + lq * 8);
#pragma unroll
    for (int mi = 0; mi < 4; ++mi)
#pragma unroll
      for (int ni = 0; ni < 4; ++ni)
        acc[mi][ni] = MFMA_16x16x32(a[mi], b[ni], acc[mi][ni]);
    __syncthreads();
  }

  // epilogue: D row=(lane>>4)*4+r (M), col=lane&15 (N)  [m89-verified mapping]
#pragma unroll
  for (int ni = 0; ni < 4; ++ni) {
    const int col = nBase + wn + ni * 16 + l15;
    float bv = 0.f;
    if (bias0) bv += bias0[col];
    if (bias1) bv += bias1[col];
#pragma unroll
    for (int mi = 0; mi < 4; ++mi) {
      const int row0 = mBase + wm + mi * 16 + lq * 4;
      f32x4 v = acc[mi][ni];
#pragma unroll
      for (int r = 0; r < 4; ++r) {
        const float out = v[r] + bv;
        if (c_is_bf16)
          ((bf16*)C)[(size_t)(row0 + r) * N + col] = __float2bfloat16(out);
        else
          ((float*)C)[(size_t)(row0 + r) * N + col] = out;
      }
    }
  }
}

// ---------------------------------------------------------------------------
// Persistent cooperative LSTM scan; supports TWO independent groups of 64
// blocks (grid 64 = group A only, grid 128 = A and B concurrently).
// Block j of a group owns h/c slice [j*16, j*16+16); wave g computes gate g.
// Whh bf16 fragments in registers. Barrier: distributed per-block flags
// (release store to own line at IF) + 64-lane parallel poll + acquire inv.
// h published via write-through (agent-scope) packed u32 stores.
// ---------------------------------------------------------------------------
__global__ __launch_bounds__(256, 1) void lstm_scan_k(
    const bf16* __restrict__ GinA, const bf16* __restrict__ WhhA,
    const float* __restrict__ c0A, bf16* __restrict__ hbufA,
    bf16* __restrict__ youtA, bf16* __restrict__ hfinA, float* __restrict__ cfinA,
    u32* __restrict__ flagsA,
    const bf16* __restrict__ GinB, const bf16* __restrict__ WhhB,
    const float* __restrict__ c0B, bf16* __restrict__ hbufB,
    bf16* __restrict__ youtB, bf16* __restrict__ hfinB, float* __restrict__ cfinB,
    u32* __restrict__ flagsB) {
  const int grp = blockIdx.x >> 6;
  const int j   = blockIdx.x & 63;
  const bf16*  Gin  = grp ? GinB  : GinA;
  const bf16*  Whh  = grp ? WhhB  : WhhA;
  const float* c0   = grp ? c0B   : c0A;
  bf16*  hbuf  = grp ? hbufB  : hbufA;
  bf16*  yout  = grp ? youtB  : youtA;
  bf16*  hfin  = grp ? hfinB  : hfinA;
  float* cfin  = grp ? cfinB  : cfinA;
  u32*   flags = grp ? flagsB : flagsA;

  const int tid = threadIdx.x;
  const int wave = tid >> 6, lane = tid & 63;
  const int l15 = lane & 15, lq = lane >> 4;

  __shared__ float gx[4][16][16];   // gate exchange (i,f,g,o)

  // preload this wave's Whh tile into registers, MFMA B-fragment order
  bf16x8 wreg[32];
  {
    const bf16* wrow = Whh + (size_t)(wave * 1024 + j * 16 + l15) * H + lq * 8;
#pragma unroll
    for (int ki = 0; ki < 32; ++ki) wreg[ki] = *(const bf16x8*)(wrow + ki * 32);
  }

  const int eb = tid >> 4, ek = tid & 15;   // elementwise: (batch, unit)
  const int hoff = eb * H + j * 16 + ek;
  float c_reg = c0 ? c0[hoff] : 0.f;

  for (int t = 0; t < S; ++t) {
    if (t > 0) {
      if (wave == 0) {
        const u32* f = flags + (size_t)lane * FSTRIDE;   // 64 lanes poll 64 flags
        while (__hip_atomic_load(f, __ATOMIC_RELAXED, __HIP_MEMORY_SCOPE_AGENT) < (u32)t) {}
      }
      __syncthreads();
      __builtin_amdgcn_fence(__ATOMIC_ACQUIRE, "agent");   // inv L1/L2, no wb
    }

    // gates = h @ Whh^T for this wave's 16 gate-rows; 4 independent MFMA chains
    const bf16* hsrc = hbuf + (size_t)(t & 1) * (Bsz * H) + (size_t)l15 * H + lq * 8;
    f32x4 ac0 = {0.f, 0.f, 0.f, 0.f}, ac1 = ac0, ac2 = ac0, ac3 = ac0;
#pragma unroll
    for (int ki = 0; ki < 32; ki += 4) {
      bf16x8 a0 = *(const bf16x8*)(hsrc + (ki + 0) * 32);
      bf16x8 a1 = *(const bf16x8*)(hsrc + (ki + 1) * 32);
      bf16x8 a2 = *(const bf16x8*)(hsrc + (ki + 2) * 32);
      bf16x8 a3 = *(const bf16x8*)(hsrc + (ki + 3) * 32);
      ac0 = MFMA_16x16x32(a0, wreg[ki + 0], ac0);
      ac1 = MFMA_16x16x32(a1, wreg[ki + 1], ac1);
      ac2 = MFMA_16x16x32(a2, wreg[ki + 2], ac2);
      ac3 = MFMA_16x16x32(a3, wreg[ki + 3], ac3);
    }
    f32x4 gacc = (ac0 + ac1) + (ac2 + ac3);
#pragma unroll
    for (int r = 0; r < 4; ++r) gx[wave][lq * 4 + r][l15] = gacc[r];
    __syncthreads();

    // elementwise LSTM cell update for (eb, ek)
    const size_t gbase = (size_t)(t * Bsz + eb) * G4 + j * 16 + ek;
    const float gi = gx[0][eb][ek] + __bfloat162float(Gin[gbase]);
    const float gf = gx[1][eb][ek] + __bfloat162float(Gin[gbase + 1024]);
    const float gg = gx[2][eb][ek] + __bfloat162float(Gin[gbase + 2048]);
    const float go = gx[3][eb][ek] + __bfloat162float(Gin[gbase + 3072]);
    const float iv = sigf(gi), fv = sigf(gf), gv = tanhf_fast(gg), ov = sigf(go);
    c_reg = fv * c_reg + iv * gv;
    const float hv = ov * tanhf_fast(c_reg);
    const u32 hbits = f2bf_bits(hv);

    // publish h: pack 2 bf16 -> u32, agent-scope write-through store (to IF)
    const u32 nbits = (u32)__shfl_down((int)hbits, 1);
    if (!(ek & 1)) {
      u32* haddr = (u32*)(hbuf + (size_t)((t + 1) & 1) * (Bsz * H) + hoff);
      __hip_atomic_store(haddr, hbits | (nbits << 16), __ATOMIC_RELAXED,
                         __HIP_MEMORY_SCOPE_AGENT);
    }
    if (yout) {
      bf16 hb = __float2bfloat16(hv);
      yout[(size_t)(t * Bsz + eb) * H + j * 16 + ek] = hb;
    }
    if (t == S - 1) {
      if (hfin) hfin[hoff] = __float2bfloat16(hv);
      if (cfin) cfin[hoff] = c_reg;
    }

    // __syncthreads drains vmcnt(0) for all waves -> h stores are at IF;
    // then release the flag (own cacheline, no RMW).
    __syncthreads();
    if (tid == 0 && t < S - 1)
      __hip_atomic_store(flags + (size_t)j * FSTRIDE, (u32)(t + 1),
                         __ATOMIC_RELAXED, __HIP_MEMORY_SCOPE_AGENT);
  }
}

// ---------------------------------------------------------------------------
// out[b, n] = he[b,:] @ latW[n,:] + latb[n]   (bf16 out [16,1024])
// grid 4, block 256
// ---------------------------------------------------------------------------
__global__ void lat_k(const bf16* __restrict__ he, const float* __restrict__ latW,
                      const float* __restrict__ latb, bf16* __restrict__ out) {
  __shared__ bf16 hs[Bsz * H];   // 32 KB
  for (int i = threadIdx.x; i < (Bsz * H) / 8; i += 256)
    ((uint4*)hs)[i] = ((const uint4*)he)[i];
  __syncthreads();

  const int n = blockIdx.x * 256 + threadIdx.x;
  const float bv = latb[n];
  float acc[Bsz];
#pragma unroll
  for (int b = 0; b < Bsz; ++b) acc[b] = bv;
  const float* wrow = latW + (size_t)n * H;
  for (int k = 0; k < H; ++k) {
    const float w = wrow[k];
#pragma unroll
    for (int b = 0; b < Bsz; ++b) acc[b] += w * __bfloat162float(hs[b * H + k]);
  }
#pragma unroll
  for (int b = 0; b < Bsz; ++b) out[b * H + n] = __float2bfloat16(acc[b]);
}

// ---------------------------------------------------------------------------
extern "C" void kernel_launch(void* const* d_in, const int* in_sizes, int n_in,
                              void* d_out, int out_size, void* d_ws, size_t ws_size,
                              hipStream_t stream) {
  (void)in_sizes; (void)n_in; (void)out_size;

  const int*   tokens   = (const int*)d_in[0];
  const float* emb      = (const float*)d_in[1];
  const float* dec_bias = (const float*)d_in[2];
  const float* Wih0 = (const float*)d_in[3];
  const float* Whh0 = (const float*)d_in[4];
  const float* bih0 = (const float*)d_in[5];
  const float* bhh0 = (const float*)d_in[6];
  const float* Wih1 = (const float*)d_in[7];
  const float* Whh1 = (const float*)d_in[8];
  const float* bih1 = (const float*)d_in[9];
  const float* bhh1 = (const float*)d_in[10];
  const float* latW = (const float*)d_in[11];
  const float* latb = (const float*)d_in[12];

  char* ws = (char*)d_ws;
  size_t off = 0;
  auto alloc = [&](size_t bytes) -> char* {
    char* p = ws + off;
    off += (bytes + 255) & ~(size_t)255;
    return p;
  };
  bf16* embB  = (bf16*)alloc((size_t)V * H * 2);     // 65.5 MB
  bf16* Wih0b = (bf16*)alloc((size_t)G4 * H * 2);    // 8.4 MB
  bf16* Whh0b = (bf16*)alloc((size_t)G4 * H * 2);
  bf16* Wih1b = (bf16*)alloc((size_t)G4 * H * 2);
  bf16* Whh1b = (bf16*)alloc((size_t)G4 * H * 2);
  bf16* x     = (bf16*)alloc((size_t)NSB * H * 2);   // 4.2 MB
  bf16* G0    = (bf16*)alloc((size_t)NSB * G4 * 2);  // 16.8 MB
  bf16* G1    = (bf16*)alloc((size_t)NSB * G4 * 2);  // reused as G2
  bf16* y0    = (bf16*)alloc((size_t)NSB * H * 2);
  bf16* d0b   = (bf16*)alloc((size_t)NSB * H * 2);
  bf16* d1b   = (bf16*)alloc((size_t)NSB * H * 2);
  bf16* hb0   = (bf16*)alloc((size_t)2 * Bsz * H * 2);   // enc0
  bf16* hb1   = (bf16*)alloc((size_t)2 * Bsz * H * 2);   // enc1
  bf16* hb2   = (bf16*)alloc((size_t)2 * Bsz * H * 2);   // dec0
  bf16* hb3   = (bf16*)alloc((size_t)2 * Bsz * H * 2);   // dec1
  bf16* he0   = (bf16*)alloc((size_t)Bsz * H * 2);
  bf16* he1   = (bf16*)alloc((size_t)Bsz * H * 2);
  float* ce0  = (float*)alloc((size_t)Bsz * H * 4);
  float* ce1  = (float*)alloc((size_t)Bsz * H * 4);
  u32* flags  = (u32*)alloc((size_t)4 * 64 * FSTRIDE * 4);   // 32 KB
  if (off > ws_size) return;

  u32* f0 = flags;
  u32* f1 = flags + 64 * FSTRIDE;
  u32* f2 = flags + 128 * FSTRIDE;
  u32* f3 = flags + 192 * FSTRIDE;

  hipMemsetAsync(flags, 0, (size_t)4 * 64 * FSTRIDE * 4, stream);
  hipMemsetAsync(hb0, 0, (size_t)Bsz * H * 2, stream);   // enc0 h_0 = 0
  hipMemsetAsync(hb1, 0, (size_t)Bsz * H * 2, stream);   // enc1 h_0 = 0

  auto cvt = [&](const float* src, bf16* dst, int n) {
    cvt_f32_bf16_k<<<(n / 4 + 255) / 256, 256, 0, stream>>>(src, dst, n / 4);
  };
  cvt(emb, embB, V * H);
  cvt(Wih0, Wih0b, G4 * H);
  cvt(Whh0, Whh0b, G4 * H);
  cvt(Wih1, Wih1b, G4 * H);
  cvt(Whh1, Whh1b, G4 * H);

  embed_k<<<NSB, 128, 0, stream>>>(tokens, embB, x);

  // G0 = x @ Wih0^T + (bih0 + bhh0)   -- shared by enc0 and dec0
  gemm_bt_k<<<dim3(NSB / 128, G4 / 128), 256, 0, stream>>>(
      x, Wih0b, bih0, bhh0, (void*)G0, NSB, G4, H, 1);

  // enc0 (single group, grid 64)
  {
    const bf16* gp = G0; const bf16* wp = Whh0b; const float* c0p = nullptr;
    bf16* hb = hb0; bf16* yo = y0; bf16* hf = he0; float* cf = ce0; u32* fp = f0;
    void* args[] = {&gp, &wp, &c0p, &hb, &yo, &hf, &cf, &fp,
                    &gp, &wp, &c0p, &hb, &yo, &hf, &cf, &fp};
    hipLaunchCooperativeKernel((void*)lstm_scan_k, dim3(64), dim3(256), args, 0, stream);
  }

  // G1 = y0 @ Wih1^T + (bih1 + bhh1)
  gemm_bt_k<<<dim3(NSB / 128, G4 / 128), 256, 0, stream>>>(
      y0, Wih1b, bih1, bhh1, (void*)G1, NSB, G4, H, 1);

  // dh0 = he0 @ latW^T + latb  -> dec0's initial h (hb2 slot 0)
  lat_k<<<4, 256, 0, stream>>>(he0, latW, latb, hb2);

  // merged: group A = enc1 (finals only), group B = dec0 (yout=d0b)
  {
    const bf16* gA = G1; const bf16* wA = Whh1b; const float* cA = nullptr;
    bf16* hA = hb1; bf16* yA = nullptr; bf16* hfA = he1; float* cfA = ce1; u32* fA = f1;
    const bf16* gB = G0; const bf16* wB = Whh0b; const float* cB = ce0;
    bf16* hB = hb2; bf16* yB = d0b; bf16* hfB = nullptr; float* cfB = nullptr; u32* fB = f2;
    void* args[] = {&gA, &wA, &cA, &hA, &yA, &hfA, &cfA, &fA,
                    &gB, &wB, &cB, &hB, &yB, &hfB, &cfB, &fB};
    hipLaunchCooperativeKernel((void*)lstm_scan_k, dim3(128), dim3(256), args, 0, stream);
  }

  // dh1 = he1 @ latW^T + latb  -> dec1's initial h (hb3 slot 0)
  lat_k<<<4, 256, 0, stream>>>(he1, latW, latb, hb3);

  // G2 = d0 @ Wih1^T + (bih1 + bhh1)  (reuse G1 buffer)
  gemm_bt_k<<<dim3(NSB / 128, G4 / 128), 256, 0, stream>>>(
      d0b, Wih1b, bih1, bhh1, (void*)G1, NSB, G4, H, 1);

  // dec1 (single group, grid 64): init (dh1, ce1), yout = d1b
  {
    const bf16* gp = G1; const bf16* wp = Whh1b; const float* c0p = ce1;
    bf16* hb = hb3; bf16* yo = d1b; bf16* hf = nullptr; float* cf = nullptr; u32* fp = f3;
    void* args[] = {&gp, &wp, &c0p, &hb, &yo, &hf, &cf, &fp,
                    &gp, &wp, &c0p, &hb, &yo, &hf, &cf, &fp};
    hipLaunchCooperativeKernel((void*)lstm_scan_k, dim3(64), dim3(256), args, 0, stream);
  }

  // logits = d1 @ embB^T + dec_bias  -> fp32 d_out [2048][32000]
  gemm_bt_k<<<dim3(NSB / 128, V / 128), 256, 0, stream>>>(
      d1b, embB, dec_bias, nullptr, d_out, NSB, V, H, 0);
}